// Round 14
// baseline (457.102 us; speedup 1.0000x reference)
//
#include <hip/hip_runtime.h>
#include <stdint.h>

#define D_IN 512
#define D_HID 256

typedef __attribute__((ext_vector_type(8))) short bf16x8;
typedef __attribute__((ext_vector_type(8))) unsigned short u16x8;
typedef __attribute__((ext_vector_type(4))) float f32x4;

__device__ __forceinline__ float b2f(unsigned short u) {
    union { float f; uint32_t i; } x; x.i = ((uint32_t)u) << 16; return x.f;
}
__device__ __forceinline__ unsigned short f2b(float f) {
    union { float f; uint32_t i; } x; x.f = f;
    uint32_t i = x.i;
    uint32_t r = (i + 0x7FFFu + ((i >> 16) & 1u)) >> 16;
    return (unsigned short)r;
}

// async global->LDS 16B copy; dest is wave-uniform base + lane*16 (HW rule)
__device__ __forceinline__ void async_copy16(const unsigned short* g, unsigned short* lds) {
    __builtin_amdgcn_global_load_lds((const __attribute__((address_space(1))) unsigned int*)g,
                                     (__attribute__((address_space(3))) unsigned int*)lds,
                                     16, 0, 0);
}

// ---------- dtype detector + counts zeroing (fused tail range) ----------
__global__ __launch_bounds__(256) void detect_dtype_kernel(const ushort4* __restrict__ raw,
        int n4, int* __restrict__ flag, int* __restrict__ counts, int N, int dblocks) {
    int b = blockIdx.x;
    if (b >= dblocks) {
        int i = (b - dblocks) * 256 + threadIdx.x;
        if (i < N) counts[i] = 0;
        return;
    }
    int i = b * 256 + threadIdx.x;
    int hit = 0;
    if (i < n4) {
        ushort4 u = raw[i];
        hit = ((((u.x >> 7) & 0xFF) == 0xFF) || (((u.y >> 7) & 0xFF) == 0xFF) ||
               (((u.z >> 7) & 0xFF) == 0xFF) || (((u.w >> 7) & 0xFF) == 0xFF)) ? 1 : 0;
    }
    unsigned long long bl = __ballot(hit);
    if ((threadIdx.x & 63) == 0 && bl != 0ULL) atomicOr(flag, 1);
}

// ---------- W pack body: fragment order ----------
//   Wp[(((kk*2 + h)*16 + c)*64 + lane)*8 + j] = W[kk*64 + h*32 + (lane>>4)*8 + j][c*16 + (lane&15)]
// One wave B-fragment load = 1 KB contiguous (validated r6).
__device__ __forceinline__ void wpack_body(const void* __restrict__ W,
        unsigned short* __restrict__ Wp, int K, bool f32, int t) {
    int total = (K >> 6) * 2 * 16 * 64;
    if (t >= total) return;
    int lane = t & 63;
    int c = (t >> 6) & 15;
    int h = (t >> 10) & 1;
    int kk = t >> 11;
    int n = c * 16 + (lane & 15);
    int k0 = kk * 64 + h * 32 + (lane >> 4) * 8;
    u16x8 o;
#pragma unroll
    for (int j = 0; j < 8; ++j) {
        float v = f32 ? ((const float*)W)[(size_t)(k0 + j) * 256 + n]
                      : b2f(((const unsigned short*)W)[(size_t)(k0 + j) * 256 + n]);
        o[j] = f2b(v);
    }
    *(u16x8*)(Wp + (size_t)t * 8) = o;
}

// ---------- fused independent pre-work: hist (long pole) + wpack1 + wpack2 ----------
// Hist captures the atomicAdd RETURN VALUE as within[e]. The returning atomic
// blocks, so each thread runs FOUR independent edges (e, e+Q, e+2Q, e+3Q) --
// four atomic round-trips in flight.
__global__ __launch_bounds__(256) void pre_fused_kernel(const int* __restrict__ dst,
        int* __restrict__ counts, int* __restrict__ within, int E,
        const void* __restrict__ W1, unsigned short* __restrict__ Wp1,
        const void* __restrict__ W2, unsigned short* __restrict__ Wp2,
        const int* __restrict__ flag, int histBlocks, int wp1Blocks) {
    int b = blockIdx.x;
    if (b < histBlocks) {
        int Q = (E + 3) >> 2;
        int e = b * 256 + threadIdx.x;
        if (e < Q) {
            int e2 = e + Q, e3 = e + 2 * Q, e4 = e + 3 * Q;
            int d1 = dst[e];
            int d2 = (e2 < E) ? dst[e2] : 0;
            int d3 = (e3 < E) ? dst[e3] : 0;
            int d4 = (e4 < E) ? dst[e4] : 0;
            int w1v = atomicAdd(&counts[d1], 1);
            int w2v = (e2 < E) ? atomicAdd(&counts[d2], 1) : 0;
            int w3v = (e3 < E) ? atomicAdd(&counts[d3], 1) : 0;
            int w4v = (e4 < E) ? atomicAdd(&counts[d4], 1) : 0;
            within[e] = w1v;
            if (e2 < E) within[e2] = w2v;
            if (e3 < E) within[e3] = w3v;
            if (e4 < E) within[e4] = w4v;
        }
        return;
    }
    b -= histBlocks;
    bool f32 = (*flag != 0);
    if (b < wp1Blocks) {
        wpack_body(W1, Wp1, D_IN, f32, b * 256 + threadIdx.x);
    } else {
        wpack_body(W2, Wp2, D_HID, f32, (b - wp1Blocks) * 256 + threadIdx.x);
    }
}

// ---------- parallel scan P1/P2/P3 ----------
__global__ __launch_bounds__(256) void partial_sum_kernel(const int* __restrict__ counts,
        int* __restrict__ partial, int n) {
    __shared__ int sh[4];
    int b = blockIdx.x;
    int lane = threadIdx.x & 63, wv = threadIdx.x >> 6;
    int s = 0;
    for (int j = threadIdx.x; j < 1024; j += 256) {
        int i = b * 1024 + j;
        s += (i < n) ? counts[i] : 0;
    }
#pragma unroll
    for (int off = 32; off > 0; off >>= 1) s += __shfl_down(s, off, 64);
    if (lane == 0) sh[wv] = s;
    __syncthreads();
    if (threadIdx.x == 0) partial[b] = sh[0] + sh[1] + sh[2] + sh[3];
}

__global__ void scan_partials_kernel(int* __restrict__ partial, int nb,
                                     int* __restrict__ indptr, int N) {
    int lane = threadIdx.x & 63;
    int orig = (lane < nb) ? partial[lane] : 0;
    int v = orig;
#pragma unroll
    for (int off = 1; off < 64; off <<= 1) {
        int u = __shfl(v, lane - off, 64);
        if (lane >= off) v += u;
    }
    int tot = __shfl(v, nb - 1, 64);
    if (lane < nb) partial[lane] = v - orig;
    if (lane == 0) indptr[N] = tot;
}

// scan_chunk also run-fills csr_dst (thread i holds its node's [start,count) --
// removes the run-fill tail from the gemm1 launch and the indptr re-read).
__global__ __launch_bounds__(1024) void scan_chunk_kernel(const int* __restrict__ counts,
        const int* __restrict__ partial, int* __restrict__ indptr,
        float* __restrict__ dinv, int* __restrict__ csr_dst, int n) {
    __shared__ int sh[1024];
    int b = blockIdx.x;
    int i = b * 1024 + threadIdx.x;
    int v = (i < n) ? counts[i] : 0;
    sh[threadIdx.x] = v;
    __syncthreads();
    for (int off = 1; off < 1024; off <<= 1) {
        int t = (threadIdx.x >= off) ? sh[threadIdx.x - off] : 0;
        __syncthreads();
        sh[threadIdx.x] += t;
        __syncthreads();
    }
    if (i < n) {
        int e = partial[b] + sh[threadIdx.x] - v;
        indptr[i] = e;
        dinv[i] = rsqrtf((float)(v + 1));
        for (int p = e; p < e + v; ++p) csr_dst[p] = i;
    }
}

// ---------- MFMA GEMM: C[M,256] = A[M,ROWSxK tiles] @ W[K,256], fused (FUSE) with
//   tail range: atomic-free CSR fill (pos = indptr[d] + within[e]).
// ROWS=32 (r14): 1563 blocks -> ~24 waves/CU resident (vs 12 at ROWS=64) for
// latency hiding; same frag layout, acc[RT=2][4], LDS 8/16 KB.
//   K=512 + f32 src: reg-staged f32->bf16, BK=64 double-buffered.
//   K=512 + bf16 src: BK=64 double-buffered async_copy16 DMA.
//   K=256 bf16 src: FULL-K staging (4 slices), ONE vmcnt(0)+barrier, 4 tiles.
// B from fragment-packed Wp (8 x 1KB coalesced/step).
// LDS per slice: 128B rows, seg rotation (seg+row)&7 (conflict-free).
template<int K, int ROWS, bool MF32, bool FUSE>
__global__ __launch_bounds__(256) void gemm_bf16(const void* __restrict__ Ain,
        const unsigned short* __restrict__ Wp, unsigned short* __restrict__ C, int M,
        const int* __restrict__ flag,
        const int* __restrict__ eidx, const int* __restrict__ within,
        int* __restrict__ csr_src, int* __restrict__ pos_of,
        const int* __restrict__ indptr, int E, int sblocks) {
    constexpr int RT = ROWS / 16;          // row-tiles of 16
    constexpr int J = ROWS / 32;           // 8-row DMA issues per wave per slice
    constexpr int NSL = (K == 256) ? 4 : 2;
    __shared__ unsigned short As[NSL][ROWS * 64];
    constexpr int NK = K / 64;
    int bid = blockIdx.x;
    int gblocks = (M + ROWS - 1) / ROWS;
    if (FUSE) {
        if (bid >= gblocks) {
            int tb = bid - gblocks;
            if (tb < sblocks) {
                int e = tb * 256 + (int)threadIdx.x;
                if (e < E) {
                    int d = eidx[(size_t)E + e];
                    int pos = indptr[d] + within[e];     // no atomic
                    csr_src[pos] = eidx[e];              // scattered store (non-blocking)
                    pos_of[e] = pos;                     // coalesced
                }
            }
            return;
        }
    }
    int t = threadIdx.x;
    int lane = t & 63, wv = t >> 6;
    int n0 = lane & 15, grp = lane >> 4;
    int row0 = bid * ROWS;

    int srow = wv * (ROWS / 4) + (lane >> 3);   // + j*8 added per issue
    int segp = lane & 7;

    f32x4 acc[RT][4];
#pragma unroll
    for (int rt = 0; rt < RT; ++rt)
#pragma unroll
        for (int ct = 0; ct < 4; ++ct) acc[rt][ct] = (f32x4){0.f, 0.f, 0.f, 0.f};

    auto compute_tile = [&](int kk, const unsigned short* Abuf) {
        bf16x8 bw[4][2];
#pragma unroll
        for (int ct = 0; ct < 4; ++ct)
#pragma unroll
            for (int h = 0; h < 2; ++h)
                bw[ct][h] = *(const bf16x8*)(Wp +
                    ((size_t)(((kk * 2 + h) * 16) + (wv * 4 + ct)) * 64 + lane) * 8);
#pragma unroll
        for (int rt = 0; rt < RT; ++rt) {
            int r = rt * 16 + n0;
#pragma unroll
            for (int h = 0; h < 2; ++h) {
                int sp = (h * 4 + grp + r) & 7;
                bf16x8 a = *(const bf16x8*)(Abuf + r * 64 + sp * 8);
#pragma unroll
                for (int ct = 0; ct < 4; ++ct)
                    acc[rt][ct] = __builtin_amdgcn_mfma_f32_16x16x32_bf16(a, bw[ct][h],
                                                                          acc[rt][ct], 0, 0, 0);
            }
        }
    };

    bool f32src = MF32 && (*flag != 0);
    if (f32src) {
        const float* A = (const float*)Ain;
        auto stage_f32 = [&](int buf, const float4* pr) {
#pragma unroll
            for (int j = 0; j < J; ++j) {
                u16x8 o;
#pragma unroll
                for (int q = 0; q < 4; ++q) {
                    o[q]     = f2b(pr[j * 2 + 0][q]);
                    o[q + 4] = f2b(pr[j * 2 + 1][q]);
                }
                *(u16x8*)(&As[buf][0] + wv * (ROWS * 16) + j * 512 + lane * 8) = o;
            }
        };
        auto load_f32 = [&](int kof, float4* pr) {
#pragma unroll
            for (int j = 0; j < J; ++j) {
                int row = srow + j * 8;
                int s = (segp - row) & 7;
                const float* g = A + (size_t)min(row0 + row, M - 1) * K + kof + s * 8;
                pr[j * 2 + 0] = *(const float4*)(g);
                pr[j * 2 + 1] = *(const float4*)(g + 4);
            }
        };
        float4 pr[2 * J];
        load_f32(0, pr);
        stage_f32(0, pr);
        for (int kk = 0; kk < NK; ++kk) {
            int cur = kk & 1;
            if (kk + 1 < NK) load_f32((kk + 1) * 64, pr);   // in flight across compute
            asm volatile("s_waitcnt lgkmcnt(0)" ::: "memory");  // my ds_writes done
            __builtin_amdgcn_s_barrier();                       // buf[cur] visible to all
            compute_tile(kk, &As[cur][0]);
            if (kk + 1 < NK) stage_f32(cur ^ 1, pr);
        }
    } else if constexpr (K == 256) {
        // full-K: stage all 4 slices up front, one drain, 4 back-to-back tiles
        const unsigned short* A = (const unsigned short*)Ain;
#pragma unroll
        for (int kk = 0; kk < 4; ++kk) {
#pragma unroll
            for (int j = 0; j < J; ++j) {
                int row = srow + j * 8;
                int s = (segp - row) & 7;
                const unsigned short* g = A + (size_t)min(row0 + row, M - 1) * K
                                           + kk * 64 + s * 8;
                async_copy16(g, &As[kk][0] + wv * (ROWS * 16) + j * 512);
            }
        }
        asm volatile("s_waitcnt vmcnt(0)" ::: "memory");
        __builtin_amdgcn_s_barrier();
#pragma unroll
        for (int kk = 0; kk < 4; ++kk) compute_tile(kk, &As[kk][0]);
    } else {
        const unsigned short* A = (const unsigned short*)Ain;
#pragma unroll
        for (int j = 0; j < J; ++j) {
            int row = srow + j * 8;
            int s = (segp - row) & 7;
            const unsigned short* g = A + (size_t)min(row0 + row, M - 1) * K + s * 8;
            async_copy16(g, &As[0][0] + wv * (ROWS * 16) + j * 512);
        }
        asm volatile("s_waitcnt vmcnt(0)" ::: "memory");
        __builtin_amdgcn_s_barrier();
        for (int kk = 0; kk < NK; ++kk) {
            int cur = kk & 1;
            if (kk + 1 < NK) {
                int kof = (kk + 1) * 64;
#pragma unroll
                for (int j = 0; j < J; ++j) {
                    int row = srow + j * 8;
                    int s = (segp - row) & 7;
                    const unsigned short* g = A + (size_t)min(row0 + row, M - 1) * K + kof + s * 8;
                    async_copy16(g, &As[cur ^ 1][0] + wv * (ROWS * 16) + j * 512);
                }
            }
            compute_tile(kk, &As[cur][0]);
            asm volatile("s_waitcnt vmcnt(0)" ::: "memory");
            __builtin_amdgcn_s_barrier();
        }
    }
#pragma unroll
    for (int rt = 0; rt < RT; ++rt) {
#pragma unroll
        for (int ct = 0; ct < 4; ++ct) {
#pragma unroll
            for (int reg = 0; reg < 4; ++reg) {
                int row = row0 + rt * 16 + grp * 4 + reg;
                if (row < M)
                    C[(size_t)row * 256 + (wv * 4 + ct) * 16 + n0] = f2b(acc[rt][ct][reg]);
            }
        }
    }
}

// ---------- GCN aggregation (bf16 h in, bf16 out, f32 accum) ----------
// Two 32-lane halves x mov-free 3-stage rotation; 6 row-loads (3 KB) in flight/wave.
// At the gather request-rate ceiling (~410 MB requested / ~64 us = 6.3 TB/s).
// r9 lesson: do NOT fuse this with LDS-heavy GEMM -- gather throughput scales with
// occupancy (68% here vs 18% fused = 159 us regression).
__global__ __launch_bounds__(256) void aggregate_kernel(const unsigned short* __restrict__ h,
        const int* __restrict__ indptr, const int* __restrict__ csr_src,
        const float* __restrict__ dinv, const void* __restrict__ bias,
        unsigned short* __restrict__ out, int n, int do_relu, const int* __restrict__ flag) {
    int wave = threadIdx.x >> 6;
    int lane = threadIdx.x & 63;
    int half = lane >> 5;
    int hl = lane & 31;
    int v = blockIdx.x * 4 + wave;
    if (v >= n) return;
    int beg = indptr[v];
    int end = indptr[v + 1];
    float dv = dinv[v];

    float acc[8];
    if (half == 0) {
        u16x8 hv = *(const u16x8*)(h + (size_t)v * 256 + hl * 8);
#pragma unroll
        for (int i = 0; i < 8; ++i) acc[i] = dv * b2f(hv[i]);
    } else {
#pragma unroll
        for (int i = 0; i < 8; ++i) acc[i] = 0.f;
    }

    float wA = 0.f, wB = 0.f, wC = 0.f;
    u16x8 rA = (u16x8)0, rB = (u16x8)0, rC = (u16x8)0;
    auto ld = [&](int idx, float& w, u16x8& r) {
        if (idx < end) {
            int s = csr_src[idx];
            w = dinv[s];
            r = *(const u16x8*)(h + (size_t)s * 256 + hl * 8);
        } else {
            w = 0.f;
        }
    };
    int e = beg + half;
    ld(e, wA, rA);
    ld(e + 2, wB, rB);
    ld(e + 4, wC, rC);
    while (e + 4 < end) {
#pragma unroll
        for (int i = 0; i < 8; ++i) acc[i] += wA * b2f(rA[i]);
        ld(e + 6, wA, rA);
#pragma unroll
        for (int i = 0; i < 8; ++i) acc[i] += wB * b2f(rB[i]);
        ld(e + 8, wB, rB);
#pragma unroll
        for (int i = 0; i < 8; ++i) acc[i] += wC * b2f(rC[i]);
        ld(e + 10, wC, rC);
        e += 6;
    }
#pragma unroll
    for (int i = 0; i < 8; ++i)
        acc[i] += wA * b2f(rA[i]) + wB * b2f(rB[i]) + wC * b2f(rC[i]);

#pragma unroll
    for (int i = 0; i < 8; ++i) acc[i] += __shfl_xor(acc[i], 32, 64);

    if (half == 0) {
        float bb[8];
        if (*flag != 0) {
            const float* bp = (const float*)bias + hl * 8;
#pragma unroll
            for (int i = 0; i < 8; ++i) bb[i] = bp[i];
        } else {
            const unsigned short* bp = (const unsigned short*)bias + hl * 8;
#pragma unroll
            for (int i = 0; i < 8; ++i) bb[i] = b2f(bp[i]);
        }
        u16x8 ov;
#pragma unroll
        for (int i = 0; i < 8; ++i) {
            float o = dv * acc[i] + bb[i];
            if (do_relu) o = fmaxf(o, 0.f);
            ov[i] = f2b(o);
        }
        *(u16x8*)(out + (size_t)v * 256 + hl * 8) = ov;
    }
}

// ---------- edge scoring via MFMA: 16 CSR-ordered edges per wave ----------
// CSR order keeps h[dst] cache-resident; h[src] is the irreducible random gather.
// Output to CSR-ordered f32 tmp (coalesced); permute pass restores edge order.
__global__ __launch_bounds__(256) void edge_score_mfma(const unsigned short* __restrict__ h,
        const int* __restrict__ csr_src, const int* __restrict__ csr_dst,
        float* __restrict__ tmp, int E) {
    int lane = threadIdx.x & 63;
    int wv = threadIdx.x >> 6;
    int base = (blockIdx.x * 4 + wv) * 16;
    if (base >= E) return;
    int m = lane & 15, grp = lane >> 4;
    int e = base + m;
    int ec = min(e, E - 1);
    int s = csr_src[ec], d = csr_dst[ec];
    const unsigned short* hs = h + (size_t)s * 256 + grp * 8;
    const unsigned short* hd = h + (size_t)d * 256 + grp * 8;
    f32x4 acc = {0.f, 0.f, 0.f, 0.f};
#pragma unroll
    for (int kk = 0; kk < 8; ++kk) {
        bf16x8 a = *(const bf16x8*)(hs + kk * 32);
        bf16x8 b = *(const bf16x8*)(hd + kk * 32);
        acc = __builtin_amdgcn_mfma_f32_16x16x32_bf16(a, b, acc, 0, 0, 0);
    }
    int reg = m - grp * 4;
    if (reg >= 0 && reg < 4 && e < E) {
        float p = (reg == 0) ? acc[0] : (reg == 1) ? acc[1] : (reg == 2) ? acc[2] : acc[3];
        tmp[e] = 1.f / (1.f + __expf(-p));   // CSR-slot order: coalesced
    }
}

// out[e] = tmp[pos_of[e]] -- L2/L3-resident gather + sequential write.
__global__ __launch_bounds__(256) void permute_out_kernel(const float* __restrict__ tmp,
        const int* __restrict__ pos_of, void* __restrict__ out, int E,
        const int* __restrict__ flag) {
    int e = blockIdx.x * blockDim.x + threadIdx.x;
    if (e >= E) return;
    float p = tmp[pos_of[e]];
    if (*flag != 0)
        ((float*)out)[e] = p;
    else
        ((unsigned short*)out)[e] = f2b(p);
}

extern "C" void kernel_launch(void* const* d_in, const int* in_sizes, int n_in,
                              void* d_out, int out_size, void* d_ws, size_t ws_size,
                              hipStream_t stream) {
    const void* x  = d_in[0];
    const int* edge_index = (const int*)d_in[1];
    const void* W1 = d_in[2];
    const void* b1 = d_in[3];
    const void* W2 = d_in[4];
    const void* b2 = d_in[5];

    const int N = in_sizes[0] / D_IN;   // 50000
    const int E = in_sizes[1] / 2;      // 800000
    const int* dst = edge_index + E;

    char* ws = (char*)d_ws;
    size_t off = 0;
    auto alloc = [&](size_t bytes) {
        char* p = ws + off;
        off = (off + bytes + 255) & ~(size_t)255;
        return p;
    };
    int* flag     = (int*)alloc(256);
    float* dinv   = (float*)alloc((size_t)N * 4);
    int* counts   = (int*)alloc((size_t)N * 4);
    int* indptr   = (int*)alloc((size_t)(N + 1) * 4);
    int* partial  = (int*)alloc(64 * 4);
    int* within   = (int*)alloc((size_t)E * 4);
    int* csr_src  = (int*)alloc((size_t)E * 4);
    int* csr_dst  = (int*)alloc((size_t)E * 4);
    int* pos_of   = (int*)alloc((size_t)E * 4);
    float* ptmp   = (float*)alloc((size_t)E * 4);
    unsigned short* Wp1 = (unsigned short*)alloc((size_t)D_IN * 256 * 2);
    unsigned short* Wp2 = (unsigned short*)alloc((size_t)D_HID * 256 * 2);
    unsigned short* hA  = (unsigned short*)alloc((size_t)N * 256 * 2);    // 25.6 MB
    unsigned short* hB  = (unsigned short*)alloc((size_t)N * 256 * 2);    // 25.6 MB

    const int nb = (N + 1023) / 1024;   // 49 <= 64
    const int Q = (E + 3) / 4;
    const int histBlocks = (Q + 255) / 256;         // 782
    const int sblocks = (E + 255) / 256;            // 3125
    const int fblocks = (N + 255) / 256;            // 196
    const int wp1Blocks = (D_IN * 32) / 256;        // 64
    const int wp2Blocks = (D_HID * 32) / 256;       // 32
    const int ggrid = (N + 31) / 32;                // 1563 (32-row tiles)
    const int dblocks = 64;

    hipMemsetAsync(flag, 0, 4, stream);
    detect_dtype_kernel<<<dblocks + fblocks, 256, 0, stream>>>(
        (const ushort4*)x, 16384, flag, counts, N, dblocks);
    pre_fused_kernel<<<histBlocks + wp1Blocks + wp2Blocks, 256, 0, stream>>>(
        dst, counts, within, E, W1, Wp1, W2, Wp2, flag, histBlocks, wp1Blocks);
    partial_sum_kernel<<<nb, 256, 0, stream>>>(counts, partial, N);
    scan_partials_kernel<<<1, 64, 0, stream>>>(partial, nb, indptr, N);
    scan_chunk_kernel<<<nb, 1024, 0, stream>>>(counts, partial, indptr, dinv, csr_dst, N);

    // gemm1 (blocks first) + atomic-free CSR fill, one launch
    gemm_bf16<D_IN, 32, true, true><<<ggrid + sblocks, 256, 0, stream>>>(
        x, Wp1, hA, N, flag, edge_index, within, csr_src, pos_of, indptr, E, sblocks);
    aggregate_kernel<<<(N + 3) / 4, 256, 0, stream>>>(hA, indptr, csr_src, dinv, b1, hB, N, 1, flag);
    gemm_bf16<D_HID, 32, false, false><<<ggrid, 256, 0, stream>>>(
        hB, Wp2, hA, N, flag, nullptr, nullptr, nullptr, nullptr, nullptr, 0, 0);
    aggregate_kernel<<<(N + 3) / 4, 256, 0, stream>>>(hA, indptr, csr_src, dinv, b2, hB, N, 0, flag);
    edge_score_mfma<<<(E + 63) / 64, 256, 0, stream>>>(hB, csr_src, csr_dst, ptmp, E);
    permute_out_kernel<<<(E + 255) / 256, 256, 0, stream>>>(ptmp, pos_of, d_out, E, flag);
}

// Round 17
// 446.046 us; speedup vs baseline: 1.0248x; 1.0248x over previous
//
#include <hip/hip_runtime.h>
#include <stdint.h>

#define D_IN 512
#define D_HID 256

typedef __attribute__((ext_vector_type(8))) short bf16x8;
typedef __attribute__((ext_vector_type(8))) unsigned short u16x8;
typedef __attribute__((ext_vector_type(4))) float f32x4;

__device__ __forceinline__ float b2f(unsigned short u) {
    union { float f; uint32_t i; } x; x.i = ((uint32_t)u) << 16; return x.f;
}
__device__ __forceinline__ unsigned short f2b(float f) {
    union { float f; uint32_t i; } x; x.f = f;
    uint32_t i = x.i;
    uint32_t r = (i + 0x7FFFu + ((i >> 16) & 1u)) >> 16;
    return (unsigned short)r;
}

// async global->LDS 16B copy; dest is wave-uniform base + lane*16 (HW rule)
__device__ __forceinline__ void async_copy16(const unsigned short* g, unsigned short* lds) {
    __builtin_amdgcn_global_load_lds((const __attribute__((address_space(1))) unsigned int*)g,
                                     (__attribute__((address_space(3))) unsigned int*)lds,
                                     16, 0, 0);
}

// ---------- dtype detector + counts zeroing (fused tail range) ----------
__global__ __launch_bounds__(256) void detect_dtype_kernel(const ushort4* __restrict__ raw,
        int n4, int* __restrict__ flag, int* __restrict__ counts, int N, int dblocks) {
    int b = blockIdx.x;
    if (b >= dblocks) {
        int i = (b - dblocks) * 256 + threadIdx.x;
        if (i < N) counts[i] = 0;
        return;
    }
    int i = b * 256 + threadIdx.x;
    int hit = 0;
    if (i < n4) {
        ushort4 u = raw[i];
        hit = ((((u.x >> 7) & 0xFF) == 0xFF) || (((u.y >> 7) & 0xFF) == 0xFF) ||
               (((u.z >> 7) & 0xFF) == 0xFF) || (((u.w >> 7) & 0xFF) == 0xFF)) ? 1 : 0;
    }
    unsigned long long bl = __ballot(hit);
    if ((threadIdx.x & 63) == 0 && bl != 0ULL) atomicOr(flag, 1);
}

// ---------- W pack body: fragment order ----------
//   Wp[(((kk*2 + h)*16 + c)*64 + lane)*8 + j] = W[kk*64 + h*32 + (lane>>4)*8 + j][c*16 + (lane&15)]
// One wave B-fragment load = 1 KB contiguous (validated r6).
__device__ __forceinline__ void wpack_body(const void* __restrict__ W,
        unsigned short* __restrict__ Wp, int K, bool f32, int t) {
    int total = (K >> 6) * 2 * 16 * 64;
    if (t >= total) return;
    int lane = t & 63;
    int c = (t >> 6) & 15;
    int h = (t >> 10) & 1;
    int kk = t >> 11;
    int n = c * 16 + (lane & 15);
    int k0 = kk * 64 + h * 32 + (lane >> 4) * 8;
    u16x8 o;
#pragma unroll
    for (int j = 0; j < 8; ++j) {
        float v = f32 ? ((const float*)W)[(size_t)(k0 + j) * 256 + n]
                      : b2f(((const unsigned short*)W)[(size_t)(k0 + j) * 256 + n]);
        o[j] = f2b(v);
    }
    *(u16x8*)(Wp + (size_t)t * 8) = o;
}

// ---------- fused independent pre-work: hist (long pole) + wpack1 + wpack2 ----------
// Hist captures the atomicAdd RETURN VALUE as within[e]. The returning atomic
// blocks, so each thread runs FOUR independent edges (e, e+Q, e+2Q, e+3Q) --
// four atomic round-trips in flight.
__global__ __launch_bounds__(256) void pre_fused_kernel(const int* __restrict__ dst,
        int* __restrict__ counts, int* __restrict__ within, int E,
        const void* __restrict__ W1, unsigned short* __restrict__ Wp1,
        const void* __restrict__ W2, unsigned short* __restrict__ Wp2,
        const int* __restrict__ flag, int histBlocks, int wp1Blocks) {
    int b = blockIdx.x;
    if (b < histBlocks) {
        int Q = (E + 3) >> 2;
        int e = b * 256 + threadIdx.x;
        if (e < Q) {
            int e2 = e + Q, e3 = e + 2 * Q, e4 = e + 3 * Q;
            int d1 = dst[e];
            int d2 = (e2 < E) ? dst[e2] : 0;
            int d3 = (e3 < E) ? dst[e3] : 0;
            int d4 = (e4 < E) ? dst[e4] : 0;
            int w1v = atomicAdd(&counts[d1], 1);
            int w2v = (e2 < E) ? atomicAdd(&counts[d2], 1) : 0;
            int w3v = (e3 < E) ? atomicAdd(&counts[d3], 1) : 0;
            int w4v = (e4 < E) ? atomicAdd(&counts[d4], 1) : 0;
            within[e] = w1v;
            if (e2 < E) within[e2] = w2v;
            if (e3 < E) within[e3] = w3v;
            if (e4 < E) within[e4] = w4v;
        }
        return;
    }
    b -= histBlocks;
    bool f32 = (*flag != 0);
    if (b < wp1Blocks) {
        wpack_body(W1, Wp1, D_IN, f32, b * 256 + threadIdx.x);
    } else {
        wpack_body(W2, Wp2, D_HID, f32, (b - wp1Blocks) * 256 + threadIdx.x);
    }
}

// ---------- parallel scan P1/P2/P3 ----------
__global__ __launch_bounds__(256) void partial_sum_kernel(const int* __restrict__ counts,
        int* __restrict__ partial, int n) {
    __shared__ int sh[4];
    int b = blockIdx.x;
    int lane = threadIdx.x & 63, wv = threadIdx.x >> 6;
    int s = 0;
    for (int j = threadIdx.x; j < 1024; j += 256) {
        int i = b * 1024 + j;
        s += (i < n) ? counts[i] : 0;
    }
#pragma unroll
    for (int off = 32; off > 0; off >>= 1) s += __shfl_down(s, off, 64);
    if (lane == 0) sh[wv] = s;
    __syncthreads();
    if (threadIdx.x == 0) partial[b] = sh[0] + sh[1] + sh[2] + sh[3];
}

__global__ void scan_partials_kernel(int* __restrict__ partial, int nb,
                                     int* __restrict__ indptr, int N) {
    int lane = threadIdx.x & 63;
    int orig = (lane < nb) ? partial[lane] : 0;
    int v = orig;
#pragma unroll
    for (int off = 1; off < 64; off <<= 1) {
        int u = __shfl(v, lane - off, 64);
        if (lane >= off) v += u;
    }
    int tot = __shfl(v, nb - 1, 64);
    if (lane < nb) partial[lane] = v - orig;
    if (lane == 0) indptr[N] = tot;
}

// scan_chunk also run-fills csr_dst (thread i holds its node's [start,count) --
// removes the run-fill tail from the gemm1 launch and the indptr re-read).
__global__ __launch_bounds__(1024) void scan_chunk_kernel(const int* __restrict__ counts,
        const int* __restrict__ partial, int* __restrict__ indptr,
        float* __restrict__ dinv, int* __restrict__ csr_dst, int n) {
    __shared__ int sh[1024];
    int b = blockIdx.x;
    int i = b * 1024 + threadIdx.x;
    int v = (i < n) ? counts[i] : 0;
    sh[threadIdx.x] = v;
    __syncthreads();
    for (int off = 1; off < 1024; off <<= 1) {
        int t = (threadIdx.x >= off) ? sh[threadIdx.x - off] : 0;
        __syncthreads();
        sh[threadIdx.x] += t;
        __syncthreads();
    }
    if (i < n) {
        int e = partial[b] + sh[threadIdx.x] - v;
        indptr[i] = e;
        dinv[i] = rsqrtf((float)(v + 1));
        for (int p = e; p < e + v; ++p) csr_dst[p] = i;
    }
}

// ---------- MFMA GEMM: C[M,256] = A[M,K] @ W[K,256], fused (FUSE) with
//   tail range: atomic-free CSR fill (pos = indptr[d] + within[e]).
// ROWS=64 (r14 lesson: 32-row tiles doubled per-block Wp traffic + overheads and
// LOST 9 us despite 45% occupancy -- the f32-staging gemm is issue-limited, not
// latency-starved; occupancy was not the binding constraint).
//   K=512 + f32 src: reg-staged f32->bf16, BK=64 double-buffered.
//   K=512 + bf16 src: BK=64 double-buffered async_copy16 DMA.
//   K=256 bf16 src: FULL-K staging (4 slices, 32 KB), ONE vmcnt(0)+barrier, 4 tiles.
// B from fragment-packed Wp (8 x 1KB coalesced/step).
// LDS per slice: 128B rows, seg rotation (seg+row)&7 (conflict-free).
template<int K, bool MF32, bool FUSE>
__global__ __launch_bounds__(256) void gemm_bf16(const void* __restrict__ Ain,
        const unsigned short* __restrict__ Wp, unsigned short* __restrict__ C, int M,
        const int* __restrict__ flag,
        const int* __restrict__ eidx, const int* __restrict__ within,
        int* __restrict__ csr_src, int* __restrict__ pos_of,
        const int* __restrict__ indptr, int E, int sblocks) {
    constexpr int NSL = (K == 256) ? 4 : 2;
    __shared__ unsigned short As[NSL][64 * 64];   // 32 KB / 16 KB
    constexpr int NK = K / 64;
    int bid = blockIdx.x;
    int gblocks = (M + 63) >> 6;
    if (FUSE) {
        if (bid >= gblocks) {
            int tb = bid - gblocks;
            if (tb < sblocks) {
                int e = tb * 256 + (int)threadIdx.x;
                if (e < E) {
                    int d = eidx[(size_t)E + e];
                    int pos = indptr[d] + within[e];     // no atomic
                    csr_src[pos] = eidx[e];              // scattered store (non-blocking)
                    pos_of[e] = pos;                     // coalesced
                }
            }
            return;
        }
    }
    int t = threadIdx.x;
    int lane = t & 63, wv = t >> 6;
    int n0 = lane & 15, grp = lane >> 4;
    int row0 = bid * 64;

    int srow = wv * 16 + (lane >> 3);         // + j*8 added per issue
    int segp = lane & 7;

    f32x4 acc[4][4];
#pragma unroll
    for (int rt = 0; rt < 4; ++rt)
#pragma unroll
        for (int ct = 0; ct < 4; ++ct) acc[rt][ct] = (f32x4){0.f, 0.f, 0.f, 0.f};

    auto compute_tile = [&](int kk, const unsigned short* Abuf) {
        bf16x8 bw[4][2];
#pragma unroll
        for (int ct = 0; ct < 4; ++ct)
#pragma unroll
            for (int h = 0; h < 2; ++h)
                bw[ct][h] = *(const bf16x8*)(Wp +
                    ((size_t)(((kk * 2 + h) * 16) + (wv * 4 + ct)) * 64 + lane) * 8);
#pragma unroll
        for (int rt = 0; rt < 4; ++rt) {
            int r = rt * 16 + n0;
#pragma unroll
            for (int h = 0; h < 2; ++h) {
                int sp = (h * 4 + grp + r) & 7;
                bf16x8 a = *(const bf16x8*)(Abuf + r * 64 + sp * 8);
#pragma unroll
                for (int ct = 0; ct < 4; ++ct)
                    acc[rt][ct] = __builtin_amdgcn_mfma_f32_16x16x32_bf16(a, bw[ct][h],
                                                                          acc[rt][ct], 0, 0, 0);
            }
        }
    };

    bool f32src = MF32 && (*flag != 0);
    if (f32src) {
        const float* A = (const float*)Ain;
        auto stage_f32 = [&](int buf, const float4* pr) {
#pragma unroll
            for (int j = 0; j < 2; ++j) {
                u16x8 o;
#pragma unroll
                for (int q = 0; q < 4; ++q) {
                    o[q]     = f2b(pr[j * 2 + 0][q]);
                    o[q + 4] = f2b(pr[j * 2 + 1][q]);
                }
                *(u16x8*)(&As[buf][0] + wv * 1024 + j * 512 + lane * 8) = o;
            }
        };
        auto load_f32 = [&](int kof, float4* pr) {
#pragma unroll
            for (int j = 0; j < 2; ++j) {
                int row = srow + j * 8;
                int s = (segp - row) & 7;
                const float* g = A + (size_t)min(row0 + row, M - 1) * K + kof + s * 8;
                pr[j * 2 + 0] = *(const float4*)(g);
                pr[j * 2 + 1] = *(const float4*)(g + 4);
            }
        };
        float4 pr[4];
        load_f32(0, pr);
        stage_f32(0, pr);
        for (int kk = 0; kk < NK; ++kk) {
            int cur = kk & 1;
            if (kk + 1 < NK) load_f32((kk + 1) * 64, pr);   // in flight across compute
            asm volatile("s_waitcnt lgkmcnt(0)" ::: "memory");  // my ds_writes done
            __builtin_amdgcn_s_barrier();                       // buf[cur] visible to all
            compute_tile(kk, &As[cur][0]);
            if (kk + 1 < NK) stage_f32(cur ^ 1, pr);
        }
    } else if constexpr (K == 256) {
        // full-K: stage all 4 slices up front, one drain, 4 back-to-back tiles
        const unsigned short* A = (const unsigned short*)Ain;
#pragma unroll
        for (int kk = 0; kk < 4; ++kk) {
#pragma unroll
            for (int j = 0; j < 2; ++j) {
                int row = srow + j * 8;
                int s = (segp - row) & 7;
                const unsigned short* g = A + (size_t)min(row0 + row, M - 1) * K
                                           + kk * 64 + s * 8;
                async_copy16(g, &As[kk][0] + wv * 1024 + j * 512);
            }
        }
        asm volatile("s_waitcnt vmcnt(0)" ::: "memory");
        __builtin_amdgcn_s_barrier();
#pragma unroll
        for (int kk = 0; kk < 4; ++kk) compute_tile(kk, &As[kk][0]);
    } else {
        const unsigned short* A = (const unsigned short*)Ain;
#pragma unroll
        for (int j = 0; j < 2; ++j) {
            int row = srow + j * 8;
            int s = (segp - row) & 7;
            const unsigned short* g = A + (size_t)min(row0 + row, M - 1) * K + s * 8;
            async_copy16(g, &As[0][0] + wv * 1024 + j * 512);
        }
        asm volatile("s_waitcnt vmcnt(0)" ::: "memory");
        __builtin_amdgcn_s_barrier();
        for (int kk = 0; kk < NK; ++kk) {
            int cur = kk & 1;
            if (kk + 1 < NK) {
                int kof = (kk + 1) * 64;
#pragma unroll
                for (int j = 0; j < 2; ++j) {
                    int row = srow + j * 8;
                    int s = (segp - row) & 7;
                    const unsigned short* g = A + (size_t)min(row0 + row, M - 1) * K + kof + s * 8;
                    async_copy16(g, &As[cur ^ 1][0] + wv * 1024 + j * 512);
                }
            }
            compute_tile(kk, &As[cur][0]);
            asm volatile("s_waitcnt vmcnt(0)" ::: "memory");
            __builtin_amdgcn_s_barrier();
        }
    }
#pragma unroll
    for (int rt = 0; rt < 4; ++rt) {
#pragma unroll
        for (int ct = 0; ct < 4; ++ct) {
#pragma unroll
            for (int reg = 0; reg < 4; ++reg) {
                int row = row0 + rt * 16 + grp * 4 + reg;
                if (row < M)
                    C[(size_t)row * 256 + (wv * 4 + ct) * 16 + n0] = f2b(acc[rt][ct][reg]);
            }
        }
    }
}

// ---------- GCN aggregation (bf16 h in, bf16 out, f32 accum) ----------
// Two 32-lane halves x mov-free 3-stage rotation; 6 row-loads (3 KB) in flight/wave.
// At the gather request-rate ceiling (~410 MB requested / ~64 us = 6.3 TB/s).
// r9 lesson: do NOT fuse this with LDS-heavy GEMM -- gather throughput scales with
// occupancy (68% here vs 18% fused = 159 us regression).
__global__ __launch_bounds__(256) void aggregate_kernel(const unsigned short* __restrict__ h,
        const int* __restrict__ indptr, const int* __restrict__ csr_src,
        const float* __restrict__ dinv, const void* __restrict__ bias,
        unsigned short* __restrict__ out, int n, int do_relu, const int* __restrict__ flag) {
    int wave = threadIdx.x >> 6;
    int lane = threadIdx.x & 63;
    int half = lane >> 5;
    int hl = lane & 31;
    int v = blockIdx.x * 4 + wave;
    if (v >= n) return;
    int beg = indptr[v];
    int end = indptr[v + 1];
    float dv = dinv[v];

    float acc[8];
    if (half == 0) {
        u16x8 hv = *(const u16x8*)(h + (size_t)v * 256 + hl * 8);
#pragma unroll
        for (int i = 0; i < 8; ++i) acc[i] = dv * b2f(hv[i]);
    } else {
#pragma unroll
        for (int i = 0; i < 8; ++i) acc[i] = 0.f;
    }

    float wA = 0.f, wB = 0.f, wC = 0.f;
    u16x8 rA = (u16x8)0, rB = (u16x8)0, rC = (u16x8)0;
    auto ld = [&](int idx, float& w, u16x8& r) {
        if (idx < end) {
            int s = csr_src[idx];
            w = dinv[s];
            r = *(const u16x8*)(h + (size_t)s * 256 + hl * 8);
        } else {
            w = 0.f;
        }
    };
    int e = beg + half;
    ld(e, wA, rA);
    ld(e + 2, wB, rB);
    ld(e + 4, wC, rC);
    while (e + 4 < end) {
#pragma unroll
        for (int i = 0; i < 8; ++i) acc[i] += wA * b2f(rA[i]);
        ld(e + 6, wA, rA);
#pragma unroll
        for (int i = 0; i < 8; ++i) acc[i] += wB * b2f(rB[i]);
        ld(e + 8, wB, rB);
#pragma unroll
        for (int i = 0; i < 8; ++i) acc[i] += wC * b2f(rC[i]);
        ld(e + 10, wC, rC);
        e += 6;
    }
#pragma unroll
    for (int i = 0; i < 8; ++i)
        acc[i] += wA * b2f(rA[i]) + wB * b2f(rB[i]) + wC * b2f(rC[i]);

#pragma unroll
    for (int i = 0; i < 8; ++i) acc[i] += __shfl_xor(acc[i], 32, 64);

    if (half == 0) {
        float bb[8];
        if (*flag != 0) {
            const float* bp = (const float*)bias + hl * 8;
#pragma unroll
            for (int i = 0; i < 8; ++i) bb[i] = bp[i];
        } else {
            const unsigned short* bp = (const unsigned short*)bias + hl * 8;
#pragma unroll
            for (int i = 0; i < 8; ++i) bb[i] = b2f(bp[i]);
        }
        u16x8 ov;
#pragma unroll
        for (int i = 0; i < 8; ++i) {
            float o = dv * acc[i] + bb[i];
            if (do_relu) o = fmaxf(o, 0.f);
            ov[i] = f2b(o);
        }
        *(u16x8*)(out + (size_t)v * 256 + hl * 8) = ov;
    }
}

// ---------- edge scoring via MFMA: 16 CSR-ordered edges per wave ----------
// CSR order keeps h[dst] cache-resident; h[src] is the irreducible random gather.
// Output to CSR-ordered f32 tmp (coalesced); permute pass restores edge order.
__global__ __launch_bounds__(256) void edge_score_mfma(const unsigned short* __restrict__ h,
        const int* __restrict__ csr_src, const int* __restrict__ csr_dst,
        float* __restrict__ tmp, int E) {
    int lane = threadIdx.x & 63;
    int wv = threadIdx.x >> 6;
    int base = (blockIdx.x * 4 + wv) * 16;
    if (base >= E) return;
    int m = lane & 15, grp = lane >> 4;
    int e = base + m;
    int ec = min(e, E - 1);
    int s = csr_src[ec], d = csr_dst[ec];
    const unsigned short* hs = h + (size_t)s * 256 + grp * 8;
    const unsigned short* hd = h + (size_t)d * 256 + grp * 8;
    f32x4 acc = {0.f, 0.f, 0.f, 0.f};
#pragma unroll
    for (int kk = 0; kk < 8; ++kk) {
        bf16x8 a = *(const bf16x8*)(hs + kk * 32);
        bf16x8 b = *(const bf16x8*)(hd + kk * 32);
        acc = __builtin_amdgcn_mfma_f32_16x16x32_bf16(a, b, acc, 0, 0, 0);
    }
    int reg = m - grp * 4;
    if (reg >= 0 && reg < 4 && e < E) {
        float p = (reg == 0) ? acc[0] : (reg == 1) ? acc[1] : (reg == 2) ? acc[2] : acc[3];
        tmp[e] = 1.f / (1.f + __expf(-p));   // CSR-slot order: coalesced
    }
}

// out[e] = tmp[pos_of[e]] -- L2/L3-resident gather + sequential write.
__global__ __launch_bounds__(256) void permute_out_kernel(const float* __restrict__ tmp,
        const int* __restrict__ pos_of, void* __restrict__ out, int E,
        const int* __restrict__ flag) {
    int e = blockIdx.x * blockDim.x + threadIdx.x;
    if (e >= E) return;
    float p = tmp[pos_of[e]];
    if (*flag != 0)
        ((float*)out)[e] = p;
    else
        ((unsigned short*)out)[e] = f2b(p);
}

extern "C" void kernel_launch(void* const* d_in, const int* in_sizes, int n_in,
                              void* d_out, int out_size, void* d_ws, size_t ws_size,
                              hipStream_t stream) {
    const void* x  = d_in[0];
    const int* edge_index = (const int*)d_in[1];
    const void* W1 = d_in[2];
    const void* b1 = d_in[3];
    const void* W2 = d_in[4];
    const void* b2 = d_in[5];

    const int N = in_sizes[0] / D_IN;   // 50000
    const int E = in_sizes[1] / 2;      // 800000
    const int* dst = edge_index + E;

    char* ws = (char*)d_ws;
    size_t off = 0;
    auto alloc = [&](size_t bytes) {
        char* p = ws + off;
        off = (off + bytes + 255) & ~(size_t)255;
        return p;
    };
    int* flag     = (int*)alloc(256);
    float* dinv   = (float*)alloc((size_t)N * 4);
    int* counts   = (int*)alloc((size_t)N * 4);
    int* indptr   = (int*)alloc((size_t)(N + 1) * 4);
    int* partial  = (int*)alloc(64 * 4);
    int* within   = (int*)alloc((size_t)E * 4);
    int* csr_src  = (int*)alloc((size_t)E * 4);
    int* csr_dst  = (int*)alloc((size_t)E * 4);
    int* pos_of   = (int*)alloc((size_t)E * 4);
    float* ptmp   = (float*)alloc((size_t)E * 4);
    unsigned short* Wp1 = (unsigned short*)alloc((size_t)D_IN * 256 * 2);
    unsigned short* Wp2 = (unsigned short*)alloc((size_t)D_HID * 256 * 2);
    unsigned short* hA  = (unsigned short*)alloc((size_t)N * 256 * 2);    // 25.6 MB
    unsigned short* hB  = (unsigned short*)alloc((size_t)N * 256 * 2);    // 25.6 MB

    const int nb = (N + 1023) / 1024;   // 49 <= 64
    const int Q = (E + 3) / 4;
    const int histBlocks = (Q + 255) / 256;         // 782
    const int sblocks = (E + 255) / 256;            // 3125
    const int fblocks = (N + 255) / 256;            // 196
    const int wp1Blocks = (D_IN * 32) / 256;        // 64
    const int wp2Blocks = (D_HID * 32) / 256;       // 32
    const int ggrid = (N + 63) / 64;                // 782 (64-row tiles)
    const int dblocks = 64;

    hipMemsetAsync(flag, 0, 4, stream);
    detect_dtype_kernel<<<dblocks + fblocks, 256, 0, stream>>>(
        (const ushort4*)x, 16384, flag, counts, N, dblocks);
    pre_fused_kernel<<<histBlocks + wp1Blocks + wp2Blocks, 256, 0, stream>>>(
        dst, counts, within, E, W1, Wp1, W2, Wp2, flag, histBlocks, wp1Blocks);
    partial_sum_kernel<<<nb, 256, 0, stream>>>(counts, partial, N);
    scan_partials_kernel<<<1, 64, 0, stream>>>(partial, nb, indptr, N);
    scan_chunk_kernel<<<nb, 1024, 0, stream>>>(counts, partial, indptr, dinv, csr_dst, N);

    // gemm1 (blocks first) + atomic-free CSR fill, one launch
    gemm_bf16<D_IN, true, true><<<ggrid + sblocks, 256, 0, stream>>>(
        x, Wp1, hA, N, flag, edge_index, within, csr_src, pos_of, indptr, E, sblocks);
    aggregate_kernel<<<(N + 3) / 4, 256, 0, stream>>>(hA, indptr, csr_src, dinv, b1, hB, N, 1, flag);
    gemm_bf16<D_HID, false, false><<<ggrid, 256, 0, stream>>>(
        hB, Wp2, hA, N, flag, nullptr, nullptr, nullptr, nullptr, nullptr, 0, 0);
    aggregate_kernel<<<(N + 3) / 4, 256, 0, stream>>>(hA, indptr, csr_src, dinv, b2, hB, N, 0, flag);
    edge_score_mfma<<<(E + 63) / 64, 256, 0, stream>>>(hB, csr_src, csr_dst, ptmp, E);
    permute_out_kernel<<<(E + 255) / 256, 256, 0, stream>>>(ptmp, pos_of, d_out, E, flag);
}